// Round 3
// baseline (299.497 us; speedup 1.0000x reference)
//
#include <hip/hip_runtime.h>
#include <hip/hip_bf16.h>

#define N_ATOMS 512
#define CDIM 64
#define NSIG 16384
#define KS 4
#define NBINS 33

// ws layout (floats): [0,32768) Dn ; [32768,294912) G ; [294912] loss acc

__global__ void k_normalize(const float* __restrict__ dict,
                            float* __restrict__ Dn, float* __restrict__ acc) {
    const int n = blockIdx.x;    // atom/column
    const int c = threadIdx.x;   // channel/row (64 threads = 1 wave)
    if (n == 0 && c == 0) *acc = 0.f;
    float v = dict[c * N_ATOMS + n];
    float sq = v * v;
    #pragma unroll
    for (int off = 32; off > 0; off >>= 1) sq += __shfl_down(sq, off);
    sq = __shfl(sq, 0);
    float m = fmaxf(sqrtf(sq), 1e-10f);
    Dn[c * N_ATOMS + n] = v / m;   // division to match reference exactly
}

__global__ void k_gram(const float* __restrict__ Dn, float* __restrict__ G) {
    __shared__ float sc[CDIM];
    const int i = blockIdx.x;
    const int t = threadIdx.x;
    if (t < CDIM) sc[t] = Dn[t * N_ATOMS + i];
    __syncthreads();
    for (int j = t; j < N_ATOMS; j += 256) {
        float a = 0.f;
        #pragma unroll
        for (int c = 0; c < CDIM; c++) a = fmaf(sc[c], Dn[c * N_ATOMS + j], a);
        G[i * N_ATOMS + j] = a;
    }
}

__device__ __forceinline__ float pick8(const float* a, int s) {
    // s is wave-uniform
    switch (s) {
        case 0: return a[0]; case 1: return a[1]; case 2: return a[2]; case 3: return a[3];
        case 4: return a[4]; case 5: return a[5]; case 6: return a[6]; default: return a[7];
    }
}

__global__ __launch_bounds__(256) void k_omp(
    const float* __restrict__ z, const float* __restrict__ Dn,
    const float* __restrict__ G, float* __restrict__ acc,
    float* __restrict__ out)
{
    const int wave = threadIdx.x >> 6;
    const int lane = threadIdx.x & 63;
    const int s = blockIdx.x * 4 + wave;        // signal index
    const int b = s >> 10;
    const int hw = s & 1023;

    // lane owns channel c=lane of this signal
    const float xch = z[(b * CDIM + lane) * 1024 + hw];

    // h_bar: lane owns atoms n = lane*8 + j
    float hb[8];
    #pragma unroll
    for (int j = 0; j < 8; j++) hb[j] = 0.f;
    for (int c = 0; c < CDIM; c++) {
        float xc = __shfl(xch, c);
        const float4* row = (const float4*)(Dn + c * N_ATOMS + lane * 8);
        float4 r0 = row[0], r1 = row[1];
        hb[0] = fmaf(r0.x, xc, hb[0]); hb[1] = fmaf(r0.y, xc, hb[1]);
        hb[2] = fmaf(r0.z, xc, hb[2]); hb[3] = fmaf(r0.w, xc, hb[3]);
        hb[4] = fmaf(r1.x, xc, hb[4]); hb[5] = fmaf(r1.y, xc, hb[5]);
        hb[6] = fmaf(r1.z, xc, hb[6]); hb[7] = fmaf(r1.w, xc, hb[7]);
    }

    float h[8];
    #pragma unroll
    for (int j = 0; j < 8; j++) h[j] = hb[j];

    unsigned sel = 0;
    int I[KS];
    float L[KS][KS];
    float coef[KS];
    float hsel[KS];
    L[0][0] = 1.f;

    #pragma unroll
    for (int k = 0; k < KS; k++) {
        // argmax of |where(selected, 0, h)|, first-max tie-break (lowest atom idx)
        float bv = -1.f; int bn = N_ATOMS;
        #pragma unroll
        for (int j = 0; j < 8; j++) {
            float v = (sel & (1u << j)) ? 0.f : fabsf(h[j]);
            if (v > bv) { bv = v; bn = lane * 8 + j; }  // ascending n: > keeps first
        }
        #pragma unroll
        for (int off = 32; off > 0; off >>= 1) {
            float ov = __shfl_down(bv, off);
            int   on = __shfl_down(bn, off);
            if (ov > bv || (ov == bv && on < bn)) { bv = ov; bn = on; }
        }
        const int idx = __shfl(bn, 0);
        if ((idx >> 3) == lane) sel |= 1u << (idx & 7);

        if (k > 0) {
            // w = solve(L[0..k), G[I_prev, idx]) ; corner = sqrt(max(1-|w|^2,1e-12))
            float w[KS - 1];
            for (int i2 = 0; i2 < k; i2++) {
                float t = G[I[i2] * N_ATOMS + idx];
                for (int j2 = 0; j2 < i2; j2++) t -= L[i2][j2] * w[j2];
                w[i2] = t / L[i2][i2];
            }
            float ssum = 0.f;
            for (int j2 = 0; j2 < k; j2++) ssum += w[j2] * w[j2];
            float corner = sqrtf(fmaxf(1.f - ssum, 1e-12f));
            for (int j2 = 0; j2 < k; j2++) L[k][j2] = w[j2];
            L[k][k] = corner;
        }
        I[k] = idx;
        hsel[k] = __shfl(pick8(hb, idx & 7), idx >> 3);   // h_bar at atom idx

        // Cholesky solve: L y = hsel ; L^T coef = y   (size k+1)
        float y[KS];
        for (int i2 = 0; i2 <= k; i2++) {
            float t = hsel[i2];
            for (int j2 = 0; j2 < i2; j2++) t -= L[i2][j2] * y[j2];
            y[i2] = t / L[i2][i2];
        }
        for (int i2 = k; i2 >= 0; i2--) {
            float t = y[i2];
            for (int j2 = i2 + 1; j2 <= k; j2++) t -= L[j2][i2] * coef[j2];
            coef[i2] = t / L[i2][i2];
        }

        // h = h_bar - x @ G  (only needed before next selection)
        if (k < KS - 1) {
            float a[8];
            #pragma unroll
            for (int j = 0; j < 8; j++) a[j] = 0.f;
            for (int m = 0; m <= k; m++) {
                const float4* gr = (const float4*)(G + I[m] * N_ATOMS + lane * 8);
                float4 g0 = gr[0], g1 = gr[1];
                float cm = coef[m];
                a[0] = fmaf(cm, g0.x, a[0]); a[1] = fmaf(cm, g0.y, a[1]);
                a[2] = fmaf(cm, g0.z, a[2]); a[3] = fmaf(cm, g0.w, a[3]);
                a[4] = fmaf(cm, g1.x, a[4]); a[5] = fmaf(cm, g1.y, a[5]);
                a[6] = fmaf(cm, g1.z, a[6]); a[7] = fmaf(cm, g1.w, a[7]);
            }
            #pragma unroll
            for (int j = 0; j < 8; j++) h[j] = hb[j] - a[j];
        }
    }

    // quantize coefficients, tokens
    int tok[KS]; float cq[KS];
    #pragma unroll
    for (int j = 0; j < KS; j++) {
        float c2 = fminf(fmaxf(coef[j], -2.f), 2.f);        // jnp.clip
        float bf = (c2 + 2.f) / 4.f * 32.f;                 // exact ref op order
        int bin = (int)rintf(bf);                           // round-half-even
        bin = bin < 0 ? 0 : (bin > 32 ? 32 : bin);
        cq[j] = -2.f + 0.125f * (float)bin;                 // exact linspace centers
        tok[j] = I[j] * NBINS + bin;
    }

    // reconstruction: z_q[c=lane] = sum_j cq[j] * Dn[lane, I[j]]
    float zq = 0.f;
    #pragma unroll
    for (int j = 0; j < KS; j++) zq = fmaf(cq[j], Dn[lane * N_ATOMS + I[j]], zq);

    float diff = zq - xch;
    float zste = xch + (zq - xch);                          // STE, same op order as ref
    out[(b * CDIM + lane) * 1024 + hw] = zste;

    float sq = diff * diff;
    #pragma unroll
    for (int off = 32; off > 0; off >>= 1) sq += __shfl_down(sq, off);
    if (lane == 0) atomicAdd(acc, sq);

    if (lane < KS)
        out[NSIG * CDIM + 1 + s * KS + lane] = (float)tok[lane];
}

__global__ void k_final(const float* __restrict__ acc, float* __restrict__ out) {
    float v = *acc / 1048576.f;           // mean((z_q - z_e)^2)
    out[NSIG * CDIM] = v + 0.25f * v;     // dl_loss + COMMIT * e_loss
}

extern "C" void kernel_launch(void* const* d_in, const int* in_sizes, int n_in,
                              void* d_out, int out_size, void* d_ws, size_t ws_size,
                              hipStream_t stream) {
    const float* z    = (const float*)d_in[0];
    const float* dict = (const float*)d_in[1];
    float* out = (float*)d_out;
    float* Dn  = (float*)d_ws;
    float* G   = Dn + 32768;
    float* acc = G + 262144;

    hipLaunchKernelGGL(k_normalize, dim3(N_ATOMS), dim3(CDIM), 0, stream, dict, Dn, acc);
    hipLaunchKernelGGL(k_gram,      dim3(N_ATOMS), dim3(256),  0, stream, Dn, G);
    hipLaunchKernelGGL(k_omp,       dim3(NSIG / 4), dim3(256), 0, stream, z, Dn, G, acc, out);
    hipLaunchKernelGGL(k_final,     dim3(1), dim3(1), 0, stream, acc, out);
}